// Round 5
// baseline (313.788 us; speedup 1.0000x reference)
//
#include <hip/hip_runtime.h>
#include <hip/hip_bf16.h>
#include <math.h>

// ---------------------------------------------------------------------------
// CLSNet forward. Shapes: B=8, C=128, H=W=128, Horg=Worg=512, NC=6, KP=8,
// NPROTO=48, PH=PW=4 (patches 32x32), M = 16*6 = 96 centers/image.
// Outputs (flat, concat): pred[8,6,512,512] | proto_expand[8,48,128] |
// p2c_sim_map[8,48,128,128] | distance_l2[8,48,16384] | proto_new[48,128]
// NOTE: harness passes integer inputs as int32 (gt is int32 on device).
// Distances use direct sum-of-squares (no p^2+f^2-2dot cancellation).
// kernA phase 3a: 768 work items on 512 threads MUST be a strided loop
// (was `if (tid<768)` -> ct[4..5] never written -> stale-LDS garbage; this
// was the round 2/3/4 failure).
// ---------------------------------------------------------------------------

#define E_M1 1.71828182845904523536f   // e - 1
#define INV_SQRT2 0.70710678118654752440f

__device__ __forceinline__ float gelu_exact(float x) {
    return 0.5f * x * (1.f + erff(x * INV_SQRT2));
}

// ---------------------------------------------------------------------------
// kern0: label map (128x128 per image) from gt subsample, class 6 -> 0
// ---------------------------------------------------------------------------
__global__ __launch_bounds__(256) void kern0(const int* __restrict__ gt,
                                             unsigned char* __restrict__ labm) {
    int idx = blockIdx.x * 256 + threadIdx.x;          // 8*128*128 = 131072
    int b = idx >> 14, y = (idx >> 7) & 127, x = idx & 127;
    int g = gt[(b * 512 + 4 * y) * 512 + 4 * x];
    labm[idx] = (unsigned char)((g == 6) ? 0 : g);
}

// ---------------------------------------------------------------------------
// kernA: per-patch segmented sums -> ctx -> LN1 -> gelu -> centers (+T)
// one block per patch (128 blocks), 512 threads
// ---------------------------------------------------------------------------
__global__ __launch_bounds__(512) void kernA(
    const float* __restrict__ feats, const unsigned char* __restrict__ labm,
    const float* __restrict__ g1, const float* __restrict__ b1,
    float* __restrict__ centers, float* __restrict__ centersT)
{
    __shared__ unsigned int lab4[256];      // 1024 mask bytes (6 bits each)
    __shared__ int cnt[6];
    __shared__ float S[4][6][128];
    __shared__ float sall[4][128];
    __shared__ float ct[6][128];

    const int tid = threadIdx.x;
    const int p = blockIdx.x;                  // 0..127
    const int b = p >> 4, pp = p & 15, ihh = pp >> 2, iww = pp & 3;

    if (tid < 6) cnt[tid] = 0;
    for (int i = tid; i < 4 * 6 * 128; i += 512) (&S[0][0][0])[i] = 0.f;
    __syncthreads();

    // ---- phase 1: per-position 6-bit indicator masks (scrambled one_hot) ----
    const unsigned char* lm = labm + b * 16384;
    for (int i = tid; i < 1024; i += 512) {
        int r = i >> 5, w = i & 31;
        int hh = ihh * 32 + r, ww = iww * 32 + w;
        int P = hh * 128 + ww;
        unsigned int m = 0;
        #pragma unroll
        for (int c = 0; c < 6; ++c) {
            int pos = c * 16384 + P;
            int hp = pos / 768;
            int rem = pos - hp * 768;
            int wp = rem / 6;
            int kp = rem - wp * 6;
            if ((int)lm[hp * 128 + wp] == kp) m |= (1u << c);
        }
        ((unsigned char*)lab4)[i] = (unsigned char)m;
        #pragma unroll
        for (int k = 0; k < 6; ++k) {
            unsigned long long bm = __ballot((m >> k) & 1u);
            if ((tid & 63) == 0) { int cc = __popcll(bm); if (cc) atomicAdd(&cnt[k], cc); }
        }
    }
    __syncthreads();

    // ---- phase 2: segmented channel sums (thread = (quarter q, channel c)) ----
    {
        const int c = tid & 127, q = tid >> 7;
        float s_all = 0.f;
        const float* fb = feats + (((long long)(b * 128 + c)) * 128 + ihh * 32 + q * 8) * 128 + iww * 32;
        float* Sq = &S[q][0][0];
        for (int r = 0; r < 8; ++r) {
            const float4* row = (const float4*)(fb + r * 128);
            const int lb = (q * 8 + r) * 32;
            for (int j = 0; j < 8; ++j) {
                float4 v = row[j];
                unsigned int l4 = lab4[(lb >> 2) + j];
                unsigned int m0 = l4 & 63u, m1 = (l4 >> 8) & 63u,
                             m2 = (l4 >> 16) & 63u, m3 = (l4 >> 24) & 63u;
                while (m0) { int k = __ffs(m0) - 1; m0 &= m0 - 1; Sq[k * 128 + c] += v.x; }
                while (m1) { int k = __ffs(m1) - 1; m1 &= m1 - 1; Sq[k * 128 + c] += v.y; }
                while (m2) { int k = __ffs(m2) - 1; m2 &= m2 - 1; Sq[k * 128 + c] += v.z; }
                while (m3) { int k = __ffs(m3) - 1; m3 &= m3 - 1; Sq[k * 128 + c] += v.w; }
                s_all += v.x + v.y + v.z + v.w;
            }
        }
        sall[q][c] = s_all;
    }
    __syncthreads();

    // ---- phase 3a: ctx closed form (768 items on 512 threads: STRIDED) ----
    for (int i = tid; i < 768; i += 512) {
        const int c = i & 127, k = i >> 7;
        float Sall = sall[0][c] + sall[1][c] + sall[2][c] + sall[3][c];
        float Sk = S[0][k][c] + S[1][k][c] + S[2][k][c] + S[3][k][c];
        float Z = fmaf((float)cnt[k], E_M1, 1024.f);
        ct[k][c] = (Sall + E_M1 * Sk) / Z;
    }
    __syncthreads();

    // ---- phase 3b: LN over C + gelu, store centers + centersT (wave per k) ----
    const int wv = tid >> 6, lane = tid & 63;
    if (wv < 6) {
        float x0 = ct[wv][lane], x1 = ct[wv][lane + 64];
        float s = x0 + x1;
        #pragma unroll
        for (int m = 1; m < 64; m <<= 1) s += __shfl_xor(s, m, 64);
        float mu = s * (1.f / 128.f);
        float d0 = x0 - mu, d1 = x1 - mu;
        float ss = d0 * d0 + d1 * d1;
        #pragma unroll
        for (int m = 1; m < 64; m <<= 1) ss += __shfl_xor(ss, m, 64);
        float inv = 1.f / sqrtf(ss * (1.f / 128.f) + 1e-6f);
        float y0 = d0 * inv * g1[lane] + b1[lane];
        float y1 = d1 * inv * g1[lane + 64] + b1[lane + 64];
        float z0 = gelu_exact(y0);
        float z1 = gelu_exact(y1);
        const int row = (b * 16 + pp) * 6 + wv;
        centers[row * 128 + lane] = z0;
        centers[row * 128 + lane + 64] = z1;
        centersT[lane * 768 + row] = z0;
        centersT[(lane + 64) * 768 + row] = z1;
    }
}

// ---------------------------------------------------------------------------
// kernC: nearest prototype per center row (argmin over 48, first-index ties)
// sum-of-squares distance (cancellation-free). 768 blocks x 64 threads
// ---------------------------------------------------------------------------
__global__ __launch_bounds__(64) void kernC(
    const float* __restrict__ centers, const float* __restrict__ proto,
    int* __restrict__ nearest)
{
    __shared__ float cr[128];
    const int row = blockIdx.x, t = threadIdx.x;
    cr[t] = centers[row * 128 + t];
    cr[t + 64] = centers[row * 128 + 64 + t];
    __syncthreads();

    float v = INFINITY; int idx = 63;
    if (t < 48) {
        const float4* pr4 = (const float4*)(proto + t * 128);
        const float4* cr4 = (const float4*)cr;
        float d2 = 0.f;
        for (int c = 0; c < 32; ++c) {
            float4 pv = pr4[c]; float4 cv = cr4[c];
            float ax = cv.x - pv.x, ay = cv.y - pv.y, az = cv.z - pv.z, aw = cv.w - pv.w;
            d2 = fmaf(ax, ax, fmaf(ay, ay, fmaf(az, az, fmaf(aw, aw, d2))));
        }
        v = sqrtf(d2);
        idx = t;
    }
    #pragma unroll
    for (int m = 1; m < 64; m <<= 1) {
        float v2 = __shfl_xor(v, m, 64);
        int i2 = __shfl_xor(idx, m, 64);
        if (v2 < v || (v2 == v && i2 < idx)) { v = v2; idx = i2; }
    }
    if (t == 0) nearest[row] = idx;
}

// ---------------------------------------------------------------------------
// kernD: momentum scan (parallel over k, ordered predicated loop)
// 48 blocks x 128 threads
// ---------------------------------------------------------------------------
__global__ __launch_bounds__(128) void kernD(
    const float* __restrict__ proto0, const int* __restrict__ nearest,
    const float* __restrict__ centersT,
    float* __restrict__ proto_new,
    float* __restrict__ out_expand, float* __restrict__ out_proto)
{
    __shared__ int nl[768];
    const int k = blockIdx.x, c = threadIdx.x;
    for (int i = c; i < 768; i += 128) nl[i] = nearest[i];
    __syncthreads();
    float p = proto0[k * 128 + c];
    const float OM = (float)(1.0 - 0.999);
    const float* col = centersT + c * 768;
    #pragma unroll 4
    for (int i = 0; i < 768; i += 4) {
        float4 v = *(const float4*)(col + i);
        if (nl[i + 0] == k) p = 0.999f * p + OM * v.x;
        if (nl[i + 1] == k) p = 0.999f * p + OM * v.y;
        if (nl[i + 2] == k) p = 0.999f * p + OM * v.z;
        if (nl[i + 3] == k) p = 0.999f * p + OM * v.w;
    }
    proto_new[k * 128 + c] = p;
    out_proto[k * 128 + c] = p;
    #pragma unroll
    for (int b = 0; b < 8; ++b) out_expand[(b * 48 + k) * 128 + c] = p;
}

// ---------------------------------------------------------------------------
// kernE: distances d^2 = sum_c (f-p)^2 (cancellation-free), LN2 over 48 +
// gelu + kp-max. grid (512 n-tiles of 32, 8 b) x 256 threads.
// LDS: fT 16KB + prot 24.75KB + dst 6.1KB = ~48KB, NO aliasing.
// thread: n2 = (t&15)*2 (2 consecutive n), kq = t>>4 (3 k)
// ---------------------------------------------------------------------------
__global__ __launch_bounds__(256) void kernE(
    const float* __restrict__ feats, const float* __restrict__ proto_new,
    const float* __restrict__ g2, const float* __restrict__ b2,
    float* __restrict__ out_sim, float* __restrict__ out_dist,
    float* __restrict__ pred_small)
{
    __shared__ float fT[128 * 32];     // fT[c][n]
    __shared__ float prot[48 * 132];   // padded rows
    __shared__ float dst[32 * 49];     // similarity 1/(1+2d), padded stride

    const int t = threadIdx.x;
    const int b = blockIdx.y;
    const int nbase = blockIdx.x * 32;

    for (int i = t; i < 6144; i += 256)
        prot[(i >> 7) * 132 + (i & 127)] = proto_new[i];
    #pragma unroll
    for (int it = 0; it < 4; ++it) {
        int idx = it * 256 + t;              // 0..1023
        int c = idx >> 3, qd = idx & 7;
        float4 v = *(const float4*)(feats + (((long long)(b * 128 + c)) << 14) + nbase + qd * 4);
        *(float4*)&fT[c * 32 + qd * 4] = v;
    }
    __syncthreads();

    const int n2 = (t & 15) * 2, k0 = (t >> 4) * 3;
    float acc[3][2];
    #pragma unroll
    for (int j = 0; j < 3; ++j) { acc[j][0] = 0.f; acc[j][1] = 0.f; }

    #pragma unroll 4
    for (int cq = 0; cq < 32; ++cq) {
        const int cb = cq * 4;
        float2 fa = *(const float2*)&fT[(cb + 0) * 32 + n2];
        float2 fb = *(const float2*)&fT[(cb + 1) * 32 + n2];
        float2 fc = *(const float2*)&fT[(cb + 2) * 32 + n2];
        float2 fd = *(const float2*)&fT[(cb + 3) * 32 + n2];
        #pragma unroll
        for (int j = 0; j < 3; ++j) {
            float4 pv = *(const float4*)&prot[(k0 + j) * 132 + cb];
            float t0, t1, t2, t3;
            t0 = fa.x - pv.x; t1 = fb.x - pv.y; t2 = fc.x - pv.z; t3 = fd.x - pv.w;
            acc[j][0] = fmaf(t0, t0, fmaf(t1, t1, fmaf(t2, t2, fmaf(t3, t3, acc[j][0]))));
            t0 = fa.y - pv.x; t1 = fb.y - pv.y; t2 = fc.y - pv.z; t3 = fd.y - pv.w;
            acc[j][1] = fmaf(t0, t0, fmaf(t1, t1, fmaf(t2, t2, fmaf(t3, t3, acc[j][1]))));
        }
    }

    #pragma unroll
    for (int j = 0; j < 3; ++j) {
        const int k = k0 + j;
        float d0 = sqrtf(acc[j][0]);
        float d1 = sqrtf(acc[j][1]);
        float2 dv; dv.x = d0; dv.y = d1;
        *(float2*)(out_dist + (((long long)(b * 48 + k)) << 14) + nbase + n2) = dv;
        dst[(n2 + 0) * 49 + k] = 1.f / (1.f + 2.f * d0);
        dst[(n2 + 1) * 49 + k] = 1.f / (1.f + 2.f * d1);
    }
    __syncthreads();

    if (t < 32) {
        const int n = t, ng = nbase + t;
        float s = 0.f;
        for (int k = 0; k < 48; ++k) s += dst[n * 49 + k];
        float mu = s * (1.f / 48.f);
        float s2 = 0.f;
        for (int k = 0; k < 48; ++k) { float d = dst[n * 49 + k] - mu; s2 = fmaf(d, d, s2); }
        float inv = 1.f / sqrtf(s2 * (1.f / 48.f) + 1e-6f);
        #pragma unroll
        for (int c6 = 0; c6 < 6; ++c6) {
            float pm = 0.f;
            #pragma unroll
            for (int kp = 0; kp < 8; ++kp) {
                int k = kp * 6 + c6;
                float y = (dst[n * 49 + k] - mu) * inv * g2[k] + b2[k];
                float z = gelu_exact(y);
                out_sim[(((long long)(b * 48 + k)) << 14) + ng] = z;
                pm = (kp == 0) ? z : fmaxf(pm, z);
            }
            pred_small[((b * 6 + c6) << 14) + ng] = pm;
        }
    }
}

// ---------------------------------------------------------------------------
// kernF: half-pixel bilinear x4 upsample (8,6,128,128)->(8,6,512,512)
// thread per 4 output x. frac cycle: r0:0.625 r1:0.875 r2:0.125 r3:0.375
// ---------------------------------------------------------------------------
__global__ __launch_bounds__(256) void kernF(
    const float* __restrict__ ps, float* __restrict__ pred)
{
    int idx = blockIdx.x * 256 + threadIdx.x;    // 8*6*512*128 = 3,145,728
    int xq = idx & 127;
    int oy = (idx >> 7) & 511;
    int bc = idx >> 16;                          // 0..47 = b*6 + c6
    int qy = oy >> 2, ry = oy & 3;
    int y0 = qy + ((ry < 2) ? -1 : 0);
    float fy = (ry == 0) ? 0.625f : (ry == 1) ? 0.875f : (ry == 2) ? 0.125f : 0.375f;
    int y0c = max(y0, 0), y1c = min(y0 + 1, 127);
    const float* base = ps + bc * 16384;
    const float* rA = base + y0c * 128;
    const float* rB = base + y1c * 128;
    int xm = max(xq - 1, 0), xp = min(xq + 1, 127);
    float a0 = rA[xm], a1 = rA[xq], a2 = rA[xp];
    float c0 = rB[xm], c1 = rB[xq], c2 = rB[xp];
    float w0 = 1.f - fy;
    float gm = w0 * a0 + fy * c0;
    float gc = w0 * a1 + fy * c1;
    float gp = w0 * a2 + fy * c2;
    float4 o;
    o.x = 0.375f * gm + 0.625f * gc;
    o.y = 0.125f * gm + 0.875f * gc;
    o.z = 0.875f * gc + 0.125f * gp;
    o.w = 0.625f * gc + 0.375f * gp;
    *(float4*)(pred + ((long long)idx << 2)) = o;
}

// ---------------------------------------------------------------------------
extern "C" void kernel_launch(void* const* d_in, const int* in_sizes, int n_in,
                              void* d_out, int out_size, void* d_ws, size_t ws_size,
                              hipStream_t stream)
{
    const float* feats = (const float*)d_in[0];
    const int* gt = (const int*)d_in[1];          // int64 in ref -> int32 on device
    const float* proto = (const float*)d_in[2];
    const float* g1 = (const float*)d_in[3];
    const float* b1 = (const float*)d_in[4];
    const float* g2 = (const float*)d_in[5];
    const float* b2 = (const float*)d_in[6];

    float* out = (float*)d_out;
    float* pred       = out;                    // 8*6*512*512   = 12,582,912
    float* out_expand = out + 12582912;         // 8*48*128      = 49,152
    float* out_sim    = out + 12632064;         // 8*48*128*128  = 6,291,456
    float* out_dist   = out + 18923520;         // 8*48*16384    = 6,291,456
    float* out_proto  = out + 25214976;         // 48*128        = 6,144

    float* ws = (float*)d_ws;
    float* centers    = ws;                     // 768*128      = 98,304
    float* centersT   = ws + 98304;             // 128*768      = 98,304
    float* proto_new  = ws + 196608;            // 48*128       = 6,144
    int*   nearest    = (int*)(ws + 202816);    // 768
    unsigned char* labm = (unsigned char*)(ws + 203584); // 131072 B = 32768 floats
    float* pred_small = ws + 236352;            // 8*6*16384 = 786,432 (ends ~4.09MB)

    kern0<<<512, 256, 0, stream>>>(gt, labm);
    kernA<<<128, 512, 0, stream>>>(feats, labm, g1, b1, centers, centersT);
    kernC<<<768, 64, 0, stream>>>(centers, proto, nearest);
    kernD<<<48, 128, 0, stream>>>(proto, nearest, centersT, proto_new,
                                  out_expand, out_proto);
    kernE<<<dim3(512, 8), 256, 0, stream>>>(feats, proto_new, g2, b2,
                                            out_sim, out_dist, pred_small);
    kernF<<<12288, 256, 0, stream>>>(pred_small, pred);
}

// Round 6
// 275.774 us; speedup vs baseline: 1.1378x; 1.1378x over previous
//
#include <hip/hip_runtime.h>
#include <hip/hip_bf16.h>
#include <math.h>

// ---------------------------------------------------------------------------
// CLSNet forward. B=8, C=128, H=W=128, Horg=Worg=512, NC=6, KP=8, NPROTO=48,
// PH=PW=4 (patches 32x32), 128 patches total, 768 center rows.
// Outputs: pred[8,6,512,512] | proto_expand[8,48,128] | p2c[8,48,128,128] |
// distance_l2[8,48,16384] | proto_new[48,128]
// gt arrives as int32. Distances: direct sum-of-squares.
// kernA split into kern0b (masks) + kernA1 (register-acc partial sums,
// 512 blocks) + kernA2 (combine+ctx+LN). kernE: packed fp32 + parallel
// epilogue. All fp op order preserved vs round-5 (bit-identical).
// ---------------------------------------------------------------------------

#define E_M1 1.71828182845904523536f   // e - 1
#define INV_SQRT2 0.70710678118654752440f

typedef float v2f __attribute__((ext_vector_type(2)));

__device__ __forceinline__ float gelu_exact(float x) {
    return 0.5f * x * (1.f + erff(x * INV_SQRT2));
}

// ---------------------------------------------------------------------------
// kern0: label map (128x128 per image), class 6 -> 0
// ---------------------------------------------------------------------------
__global__ __launch_bounds__(256) void kern0(const int* __restrict__ gt,
                                             unsigned char* __restrict__ labm) {
    int idx = blockIdx.x * 256 + threadIdx.x;          // 131072
    int b = idx >> 14, y = (idx >> 7) & 127, x = idx & 127;
    int g = gt[(b * 512 + 4 * y) * 512 + 4 * x];
    labm[idx] = (unsigned char)((g == 6) ? 0 : g);
}

// ---------------------------------------------------------------------------
// kern0b: scrambled one-hot 6-bit mask per (b,P) from labm
// ---------------------------------------------------------------------------
__global__ __launch_bounds__(256) void kern0b(const unsigned char* __restrict__ labm,
                                              unsigned char* __restrict__ maskb) {
    int idx = blockIdx.x * 256 + threadIdx.x;          // 131072
    int b = idx >> 14, P = idx & 16383;
    const unsigned char* lm = labm + b * 16384;
    unsigned int m = 0;
    #pragma unroll
    for (int c = 0; c < 6; ++c) {
        int pos = c * 16384 + P;
        int hp = pos / 768;
        int rem = pos - hp * 768;
        int wp = rem / 6;
        int kp = rem - wp * 6;
        if ((int)lm[hp * 128 + wp] == kp) m |= (1u << c);
    }
    maskb[idx] = (unsigned char)m;
}

// ---------------------------------------------------------------------------
// kernA1: per-(patch,quarter) segmented channel sums in REGISTERS.
// 512 blocks (patch*4+q) x 128 threads (c). part[pidx][7][128].
// ---------------------------------------------------------------------------
__global__ __launch_bounds__(128) void kernA1(
    const float* __restrict__ feats, const unsigned char* __restrict__ maskb,
    float* __restrict__ part)
{
    const int pidx = blockIdx.x;
    const int patch = pidx >> 2, q = pidx & 3;
    const int b = patch >> 4, pp = patch & 15, ihh = pp >> 2, iww = pp & 3;
    const int c = threadIdx.x;

    const float* fb = feats + (((long long)(b * 128 + c)) * 128 + ihh * 32 + q * 8) * 128 + iww * 32;
    const unsigned char* mb = maskb + b * 16384 + (ihh * 32 + q * 8) * 128 + iww * 32;

    float s0 = 0.f, s1 = 0.f, s2 = 0.f, s3 = 0.f, s4 = 0.f, s5 = 0.f, sall = 0.f;
    for (int r = 0; r < 8; ++r) {
        const float4* row = (const float4*)(fb + r * 128);
        const unsigned int* mr = (const unsigned int*)(mb + r * 128);
        #pragma unroll
        for (int j = 0; j < 8; ++j) {
            float4 v = row[j];
            unsigned int u = mr[j];
            unsigned int b0 = u, b1 = u >> 8, b2 = u >> 16, b3 = u >> 24;
            s0 += ((b0 >> 0) & 1) ? v.x : 0.f;  s1 += ((b0 >> 1) & 1) ? v.x : 0.f;
            s2 += ((b0 >> 2) & 1) ? v.x : 0.f;  s3 += ((b0 >> 3) & 1) ? v.x : 0.f;
            s4 += ((b0 >> 4) & 1) ? v.x : 0.f;  s5 += ((b0 >> 5) & 1) ? v.x : 0.f;
            s0 += ((b1 >> 0) & 1) ? v.y : 0.f;  s1 += ((b1 >> 1) & 1) ? v.y : 0.f;
            s2 += ((b1 >> 2) & 1) ? v.y : 0.f;  s3 += ((b1 >> 3) & 1) ? v.y : 0.f;
            s4 += ((b1 >> 4) & 1) ? v.y : 0.f;  s5 += ((b1 >> 5) & 1) ? v.y : 0.f;
            s0 += ((b2 >> 0) & 1) ? v.z : 0.f;  s1 += ((b2 >> 1) & 1) ? v.z : 0.f;
            s2 += ((b2 >> 2) & 1) ? v.z : 0.f;  s3 += ((b2 >> 3) & 1) ? v.z : 0.f;
            s4 += ((b2 >> 4) & 1) ? v.z : 0.f;  s5 += ((b2 >> 5) & 1) ? v.z : 0.f;
            s0 += ((b3 >> 0) & 1) ? v.w : 0.f;  s1 += ((b3 >> 1) & 1) ? v.w : 0.f;
            s2 += ((b3 >> 2) & 1) ? v.w : 0.f;  s3 += ((b3 >> 3) & 1) ? v.w : 0.f;
            s4 += ((b3 >> 4) & 1) ? v.w : 0.f;  s5 += ((b3 >> 5) & 1) ? v.w : 0.f;
            sall += v.x + v.y + v.z + v.w;
        }
    }
    float* po = part + pidx * 896;
    po[0 * 128 + c] = s0; po[1 * 128 + c] = s1; po[2 * 128 + c] = s2;
    po[3 * 128 + c] = s3; po[4 * 128 + c] = s4; po[5 * 128 + c] = s5;
    po[6 * 128 + c] = sall;
}

// ---------------------------------------------------------------------------
// kernA2: combine quarters -> ctx -> LN1 -> gelu -> centers (+T)
// 128 blocks (patch) x 512 threads
// ---------------------------------------------------------------------------
__global__ __launch_bounds__(512) void kernA2(
    const float* __restrict__ part, const unsigned char* __restrict__ maskb,
    const float* __restrict__ g1, const float* __restrict__ b1,
    float* __restrict__ centers, float* __restrict__ centersT)
{
    __shared__ float ct[6][128];
    __shared__ int cnt[6];

    const int tid = threadIdx.x;
    const int p = blockIdx.x;                  // 0..127
    const int b = p >> 4, pp = p & 15, ihh = pp >> 2, iww = pp & 3;

    if (tid < 6) cnt[tid] = 0;
    __syncthreads();

    // ---- counts from mask bytes (256 threads x 4 bytes, wave-reduced) ----
    if (tid < 256) {
        const unsigned char* mb = maskb + b * 16384 + ihh * 32 * 128 + iww * 32;
        int r = tid >> 3, jw = tid & 7;
        unsigned int u = *(const unsigned int*)(mb + r * 128 + jw * 4);
        #pragma unroll
        for (int k = 0; k < 6; ++k) {
            int cc = ((u >> k) & 1) + ((u >> (8 + k)) & 1) +
                     ((u >> (16 + k)) & 1) + ((u >> (24 + k)) & 1);
            #pragma unroll
            for (int m = 1; m < 64; m <<= 1) cc += __shfl_xor(cc, m, 64);
            if ((tid & 63) == 0 && cc) atomicAdd(&cnt[k], cc);
        }
    }
    __syncthreads();

    // ---- ctx closed form (strided over 768) ----
    const float* pb = part + (p * 4) * 896;
    for (int i = tid; i < 768; i += 512) {
        const int c = i & 127, k = i >> 7;
        float Sall = pb[6 * 128 + c] + pb[896 + 6 * 128 + c] +
                     pb[2 * 896 + 6 * 128 + c] + pb[3 * 896 + 6 * 128 + c];
        float Sk = pb[k * 128 + c] + pb[896 + k * 128 + c] +
                   pb[2 * 896 + k * 128 + c] + pb[3 * 896 + k * 128 + c];
        float Z = fmaf((float)cnt[k], E_M1, 1024.f);
        ct[k][c] = (Sall + E_M1 * Sk) / Z;
    }
    __syncthreads();

    // ---- LN over C + gelu, store centers + centersT (wave per k) ----
    const int wv = tid >> 6, lane = tid & 63;
    if (wv < 6) {
        float x0 = ct[wv][lane], x1 = ct[wv][lane + 64];
        float s = x0 + x1;
        #pragma unroll
        for (int m = 1; m < 64; m <<= 1) s += __shfl_xor(s, m, 64);
        float mu = s * (1.f / 128.f);
        float d0 = x0 - mu, d1 = x1 - mu;
        float ss = d0 * d0 + d1 * d1;
        #pragma unroll
        for (int m = 1; m < 64; m <<= 1) ss += __shfl_xor(ss, m, 64);
        float inv = 1.f / sqrtf(ss * (1.f / 128.f) + 1e-6f);
        float y0 = d0 * inv * g1[lane] + b1[lane];
        float y1 = d1 * inv * g1[lane + 64] + b1[lane + 64];
        float z0 = gelu_exact(y0);
        float z1 = gelu_exact(y1);
        const int row = (b * 16 + pp) * 6 + wv;
        centers[row * 128 + lane] = z0;
        centers[row * 128 + lane + 64] = z1;
        centersT[lane * 768 + row] = z0;
        centersT[(lane + 64) * 768 + row] = z1;
    }
}

// ---------------------------------------------------------------------------
// kernC: nearest prototype per center row (argmin 48, first-index ties)
// ---------------------------------------------------------------------------
__global__ __launch_bounds__(64) void kernC(
    const float* __restrict__ centers, const float* __restrict__ proto,
    int* __restrict__ nearest)
{
    __shared__ float cr[128];
    const int row = blockIdx.x, t = threadIdx.x;
    cr[t] = centers[row * 128 + t];
    cr[t + 64] = centers[row * 128 + 64 + t];
    __syncthreads();

    float v = INFINITY; int idx = 63;
    if (t < 48) {
        const float4* pr4 = (const float4*)(proto + t * 128);
        const float4* cr4 = (const float4*)cr;
        float d2 = 0.f;
        for (int c = 0; c < 32; ++c) {
            float4 pv = pr4[c]; float4 cv = cr4[c];
            float ax = cv.x - pv.x, ay = cv.y - pv.y, az = cv.z - pv.z, aw = cv.w - pv.w;
            d2 = fmaf(ax, ax, fmaf(ay, ay, fmaf(az, az, fmaf(aw, aw, d2))));
        }
        v = sqrtf(d2);
        idx = t;
    }
    #pragma unroll
    for (int m = 1; m < 64; m <<= 1) {
        float v2 = __shfl_xor(v, m, 64);
        int i2 = __shfl_xor(idx, m, 64);
        if (v2 < v || (v2 == v && i2 < idx)) { v = v2; idx = i2; }
    }
    if (t == 0) nearest[row] = idx;
}

// ---------------------------------------------------------------------------
// kernD: momentum scan (parallel over k, ordered predicated loop)
// ---------------------------------------------------------------------------
__global__ __launch_bounds__(128) void kernD(
    const float* __restrict__ proto0, const int* __restrict__ nearest,
    const float* __restrict__ centersT,
    float* __restrict__ proto_new,
    float* __restrict__ out_expand, float* __restrict__ out_proto)
{
    __shared__ int nl[768];
    const int k = blockIdx.x, c = threadIdx.x;
    for (int i = c; i < 768; i += 128) nl[i] = nearest[i];
    __syncthreads();
    float p = proto0[k * 128 + c];
    const float OM = (float)(1.0 - 0.999);
    const float* col = centersT + c * 768;
    #pragma unroll 4
    for (int i = 0; i < 768; i += 4) {
        float4 v = *(const float4*)(col + i);
        if (nl[i + 0] == k) p = 0.999f * p + OM * v.x;
        if (nl[i + 1] == k) p = 0.999f * p + OM * v.y;
        if (nl[i + 2] == k) p = 0.999f * p + OM * v.z;
        if (nl[i + 3] == k) p = 0.999f * p + OM * v.w;
    }
    proto_new[k * 128 + c] = p;
    out_proto[k * 128 + c] = p;
    #pragma unroll
    for (int b = 0; b < 8; ++b) out_expand[(b * 48 + k) * 128 + c] = p;
}

// ---------------------------------------------------------------------------
// kernE: d^2 = sum_c (f-p)^2 via packed fp32, LN2 + gelu + kp-max with
// parallel epilogue. grid (512 n-tiles of 32, 8 b) x 256 threads. ~48KB LDS.
// ---------------------------------------------------------------------------
__global__ __launch_bounds__(256) void kernE(
    const float* __restrict__ feats, const float* __restrict__ proto_new,
    const float* __restrict__ g2, const float* __restrict__ b2,
    float* __restrict__ out_sim, float* __restrict__ out_dist,
    float* __restrict__ pred_small)
{
    __shared__ float fT[128 * 32];     // fT[c][n]
    __shared__ float prot[48 * 132];   // padded rows
    __shared__ float dst[32 * 49];     // similarity 1/(1+2d)
    __shared__ float muv[32], invv[32];

    const int t = threadIdx.x;
    const int b = blockIdx.y;
    const int nbase = blockIdx.x * 32;

    for (int i = t; i < 6144; i += 256)
        prot[(i >> 7) * 132 + (i & 127)] = proto_new[i];
    #pragma unroll
    for (int it = 0; it < 4; ++it) {
        int idx = it * 256 + t;              // 0..1023
        int c = idx >> 3, qd = idx & 7;
        float4 v = *(const float4*)(feats + (((long long)(b * 128 + c)) << 14) + nbase + qd * 4);
        *(float4*)&fT[c * 32 + qd * 4] = v;
    }
    __syncthreads();

    const int n2 = (t & 15) * 2, k0 = (t >> 4) * 3;
    v2f acc[3];
    #pragma unroll
    for (int j = 0; j < 3; ++j) acc[j] = (v2f)(0.f);

    #pragma unroll 4
    for (int cq = 0; cq < 32; ++cq) {
        const int cb = cq * 4;
        v2f fa = *(const v2f*)&fT[(cb + 0) * 32 + n2];
        v2f fb = *(const v2f*)&fT[(cb + 1) * 32 + n2];
        v2f fc = *(const v2f*)&fT[(cb + 2) * 32 + n2];
        v2f fd = *(const v2f*)&fT[(cb + 3) * 32 + n2];
        #pragma unroll
        for (int j = 0; j < 3; ++j) {
            float4 pv = *(const float4*)&prot[(k0 + j) * 132 + cb];
            v2f t0 = fa - pv.x, t1 = fb - pv.y, t2 = fc - pv.z, t3 = fd - pv.w;
            // same nesting order as scalar version: t3 innermost
            acc[j] = __builtin_elementwise_fma(t0, t0,
                     __builtin_elementwise_fma(t1, t1,
                     __builtin_elementwise_fma(t2, t2,
                     __builtin_elementwise_fma(t3, t3, acc[j]))));
        }
    }

    #pragma unroll
    for (int j = 0; j < 3; ++j) {
        const int k = k0 + j;
        float d0 = sqrtf(acc[j].x);
        float d1 = sqrtf(acc[j].y);
        float2 dv; dv.x = d0; dv.y = d1;
        *(float2*)(out_dist + (((long long)(b * 48 + k)) << 14) + nbase + n2) = dv;
        dst[(n2 + 0) * 49 + k] = 1.f / (1.f + 2.f * d0);
        dst[(n2 + 1) * 49 + k] = 1.f / (1.f + 2.f * d1);
    }
    __syncthreads();

    // stage 1: LN stats per n (cheap, 32 threads)
    if (t < 32) {
        const int n = t;
        float s = 0.f;
        for (int k = 0; k < 48; ++k) s += dst[n * 49 + k];
        float mu = s * (1.f / 48.f);
        float s2 = 0.f;
        for (int k = 0; k < 48; ++k) { float d = dst[n * 49 + k] - mu; s2 = fmaf(d, d, s2); }
        muv[n] = mu;
        invv[n] = 1.f / sqrtf(s2 * (1.f / 48.f) + 1e-6f);
    }
    __syncthreads();

    // stage 2: gelu + out_sim + kp-max, parallel over (c6, n) = 192 threads
    if (t < 192) {
        const int c6 = t >> 5, n = t & 31, ng = nbase + n;
        float mu = muv[n], inv = invv[n];
        float pm = 0.f;
        #pragma unroll
        for (int kp = 0; kp < 8; ++kp) {
            int k = kp * 6 + c6;
            float y = (dst[n * 49 + k] - mu) * inv * g2[k] + b2[k];
            float z = gelu_exact(y);
            out_sim[(((long long)(b * 48 + k)) << 14) + ng] = z;
            pm = (kp == 0) ? z : fmaxf(pm, z);
        }
        pred_small[((b * 6 + c6) << 14) + ng] = pm;
    }
}

// ---------------------------------------------------------------------------
// kernF: half-pixel bilinear x4 upsample (8,6,128,128)->(8,6,512,512)
// ---------------------------------------------------------------------------
__global__ __launch_bounds__(256) void kernF(
    const float* __restrict__ ps, float* __restrict__ pred)
{
    int idx = blockIdx.x * 256 + threadIdx.x;    // 3,145,728
    int xq = idx & 127;
    int oy = (idx >> 7) & 511;
    int bc = idx >> 16;
    int qy = oy >> 2, ry = oy & 3;
    int y0 = qy + ((ry < 2) ? -1 : 0);
    float fy = (ry == 0) ? 0.625f : (ry == 1) ? 0.875f : (ry == 2) ? 0.125f : 0.375f;
    int y0c = max(y0, 0), y1c = min(y0 + 1, 127);
    const float* base = ps + bc * 16384;
    const float* rA = base + y0c * 128;
    const float* rB = base + y1c * 128;
    int xm = max(xq - 1, 0), xp = min(xq + 1, 127);
    float a0 = rA[xm], a1 = rA[xq], a2 = rA[xp];
    float c0 = rB[xm], c1 = rB[xq], c2 = rB[xp];
    float w0 = 1.f - fy;
    float gm = w0 * a0 + fy * c0;
    float gc = w0 * a1 + fy * c1;
    float gp = w0 * a2 + fy * c2;
    float4 o;
    o.x = 0.375f * gm + 0.625f * gc;
    o.y = 0.125f * gm + 0.875f * gc;
    o.z = 0.875f * gc + 0.125f * gp;
    o.w = 0.625f * gc + 0.375f * gp;
    *(float4*)(pred + ((long long)idx << 2)) = o;
}

// ---------------------------------------------------------------------------
extern "C" void kernel_launch(void* const* d_in, const int* in_sizes, int n_in,
                              void* d_out, int out_size, void* d_ws, size_t ws_size,
                              hipStream_t stream)
{
    const float* feats = (const float*)d_in[0];
    const int* gt = (const int*)d_in[1];
    const float* proto = (const float*)d_in[2];
    const float* g1 = (const float*)d_in[3];
    const float* b1 = (const float*)d_in[4];
    const float* g2 = (const float*)d_in[5];
    const float* b2 = (const float*)d_in[6];

    float* out = (float*)d_out;
    float* pred       = out;
    float* out_expand = out + 12582912;
    float* out_sim    = out + 12632064;
    float* out_dist   = out + 18923520;
    float* out_proto  = out + 25214976;

    float* ws = (float*)d_ws;
    float* centers    = ws;                     // 98,304
    float* centersT   = ws + 98304;             // 98,304
    float* proto_new  = ws + 196608;            // 6,144
    int*   nearest    = (int*)(ws + 202752);    // 768
    float* part       = ws + 203520;            // 512*896 = 458,752
    float* pred_small = ws + 203520;            // ALIASED with part: kernE
                                                // writes after kernA2 reads
    unsigned char* labm  = (unsigned char*)(ws + 989952);  // 131,072 B
    unsigned char* maskb = labm + 131072;                  // 131,072 B

    kern0 <<<512, 256, 0, stream>>>(gt, labm);
    kern0b<<<512, 256, 0, stream>>>(labm, maskb);
    kernA1<<<512, 128, 0, stream>>>(feats, maskb, part);
    kernA2<<<128, 512, 0, stream>>>(part, maskb, g1, b1, centers, centersT);
    kernC <<<768, 64, 0, stream>>>(centers, proto, nearest);
    kernD <<<48, 128, 0, stream>>>(proto, nearest, centersT, proto_new,
                                   out_expand, out_proto);
    kernE <<<dim3(512, 8), 256, 0, stream>>>(feats, proto_new, g2, b2,
                                             out_sim, out_dist, pred_small);
    kernF <<<12288, 256, 0, stream>>>(pred_small, pred);
}

// Round 7
// 267.555 us; speedup vs baseline: 1.1728x; 1.0307x over previous
//
#include <hip/hip_runtime.h>
#include <hip/hip_bf16.h>
#include <math.h>

// ---------------------------------------------------------------------------
// CLSNet forward. B=8, C=128, H=W=128, Horg=Worg=512, NC=6, KP=8, NPROTO=48,
// PH=PW=4 (patches 32x32), 128 patches, 768 center rows.
// Outputs: pred[8,6,512,512] | proto_expand[8,48,128] | p2c[8,48,128,128] |
// distance_l2[8,48,16384] | proto_new[48,128]
// gt arrives as int32.
// kernE v3: dot-form d^2 = clamp(F2[n] + P2[k] - 2*dot, 0) (fp32 error ~3e-5,
// safe — round-2's failure was the kernA uninit bug, not cancellation).
// 64-n tile, 4n x 3k per thread, all-b128 LDS reads (LDS-issue-bound before).
// kern0+kern0b fused; kernC argmin fused into kernA2; kernD computes pn2.
// ---------------------------------------------------------------------------

#define E_M1 1.71828182845904523536f   // e - 1
#define INV_SQRT2 0.70710678118654752440f

typedef float v2f __attribute__((ext_vector_type(2)));

__device__ __forceinline__ float gelu_exact(float x) {
    return 0.5f * x * (1.f + erff(x * INV_SQRT2));
}
__device__ __forceinline__ v2f splat2(float x) { v2f r; r.x = x; r.y = x; return r; }

// ---------------------------------------------------------------------------
// kern0b: scrambled one-hot 6-bit mask per (b,P) directly from gt
// ---------------------------------------------------------------------------
__global__ __launch_bounds__(256) void kern0b(const int* __restrict__ gt,
                                              unsigned char* __restrict__ maskb) {
    int idx = blockIdx.x * 256 + threadIdx.x;          // 131072
    int b = idx >> 14, P = idx & 16383;
    const int* gb = gt + b * 262144;
    unsigned int m = 0;
    #pragma unroll
    for (int c = 0; c < 6; ++c) {
        int pos = c * 16384 + P;
        int hp = pos / 768;
        int rem = pos - hp * 768;
        int wp = rem / 6;
        int kp = rem - wp * 6;
        int g = gb[(4 * hp) * 512 + 4 * wp];
        int lab = (g == 6) ? 0 : g;
        if (lab == kp) m |= (1u << c);
    }
    maskb[idx] = (unsigned char)m;
}

// ---------------------------------------------------------------------------
// kernA1: per-(patch,quarter) segmented channel sums in registers.
// 512 blocks (patch*4+q) x 128 threads (c). part[pidx][7][128].
// ---------------------------------------------------------------------------
__global__ __launch_bounds__(128) void kernA1(
    const float* __restrict__ feats, const unsigned char* __restrict__ maskb,
    float* __restrict__ part)
{
    const int pidx = blockIdx.x;
    const int patch = pidx >> 2, q = pidx & 3;
    const int b = patch >> 4, pp = patch & 15, ihh = pp >> 2, iww = pp & 3;
    const int c = threadIdx.x;

    const float* fb = feats + (((long long)(b * 128 + c)) * 128 + ihh * 32 + q * 8) * 128 + iww * 32;
    const unsigned char* mb = maskb + b * 16384 + (ihh * 32 + q * 8) * 128 + iww * 32;

    float s0 = 0.f, s1 = 0.f, s2 = 0.f, s3 = 0.f, s4 = 0.f, s5 = 0.f, sall = 0.f;
    for (int r = 0; r < 8; ++r) {
        const float4* row = (const float4*)(fb + r * 128);
        const unsigned int* mr = (const unsigned int*)(mb + r * 128);
        #pragma unroll
        for (int j = 0; j < 8; ++j) {
            float4 v = row[j];
            unsigned int u = mr[j];
            unsigned int b0 = u, b1 = u >> 8, b2 = u >> 16, b3 = u >> 24;
            s0 += ((b0 >> 0) & 1) ? v.x : 0.f;  s1 += ((b0 >> 1) & 1) ? v.x : 0.f;
            s2 += ((b0 >> 2) & 1) ? v.x : 0.f;  s3 += ((b0 >> 3) & 1) ? v.x : 0.f;
            s4 += ((b0 >> 4) & 1) ? v.x : 0.f;  s5 += ((b0 >> 5) & 1) ? v.x : 0.f;
            s0 += ((b1 >> 0) & 1) ? v.y : 0.f;  s1 += ((b1 >> 1) & 1) ? v.y : 0.f;
            s2 += ((b1 >> 2) & 1) ? v.y : 0.f;  s3 += ((b1 >> 3) & 1) ? v.y : 0.f;
            s4 += ((b1 >> 4) & 1) ? v.y : 0.f;  s5 += ((b1 >> 5) & 1) ? v.y : 0.f;
            s0 += ((b2 >> 0) & 1) ? v.z : 0.f;  s1 += ((b2 >> 1) & 1) ? v.z : 0.f;
            s2 += ((b2 >> 2) & 1) ? v.z : 0.f;  s3 += ((b2 >> 3) & 1) ? v.z : 0.f;
            s4 += ((b2 >> 4) & 1) ? v.z : 0.f;  s5 += ((b2 >> 5) & 1) ? v.z : 0.f;
            s0 += ((b3 >> 0) & 1) ? v.w : 0.f;  s1 += ((b3 >> 1) & 1) ? v.w : 0.f;
            s2 += ((b3 >> 2) & 1) ? v.w : 0.f;  s3 += ((b3 >> 3) & 1) ? v.w : 0.f;
            s4 += ((b3 >> 4) & 1) ? v.w : 0.f;  s5 += ((b3 >> 5) & 1) ? v.w : 0.f;
            sall += v.x + v.y + v.z + v.w;
        }
    }
    float* po = part + pidx * 896;
    po[0 * 128 + c] = s0; po[1 * 128 + c] = s1; po[2 * 128 + c] = s2;
    po[3 * 128 + c] = s3; po[4 * 128 + c] = s4; po[5 * 128 + c] = s5;
    po[6 * 128 + c] = sall;
}

// ---------------------------------------------------------------------------
// kernA2: combine quarters -> ctx -> LN1 -> gelu -> centersT + fused argmin
// (nearest prototype, first-index ties). 128 blocks x 512 threads.
// ---------------------------------------------------------------------------
__global__ __launch_bounds__(512) void kernA2(
    const float* __restrict__ part, const unsigned char* __restrict__ maskb,
    const float* __restrict__ proto,
    const float* __restrict__ g1, const float* __restrict__ b1,
    float* __restrict__ centersT, int* __restrict__ nearest)
{
    __shared__ float ct[6][128];
    __shared__ int cnt[6];
    __shared__ float pl[48 * 129];     // proto, stride 129 -> 2-way banks (free)

    const int tid = threadIdx.x;
    const int p = blockIdx.x;                  // 0..127
    const int b = p >> 4, pp = p & 15, ihh = pp >> 2, iww = pp & 3;

    if (tid < 6) cnt[tid] = 0;
    for (int i = tid; i < 6144; i += 512)
        pl[(i >> 7) * 129 + (i & 127)] = proto[i];
    __syncthreads();

    // ---- counts from mask bytes (256 threads x 4 bytes, wave-reduced) ----
    if (tid < 256) {
        const unsigned char* mb = maskb + b * 16384 + ihh * 32 * 128 + iww * 32;
        int r = tid >> 3, jw = tid & 7;
        unsigned int u = *(const unsigned int*)(mb + r * 128 + jw * 4);
        #pragma unroll
        for (int k = 0; k < 6; ++k) {
            int cc = ((u >> k) & 1) + ((u >> (8 + k)) & 1) +
                     ((u >> (16 + k)) & 1) + ((u >> (24 + k)) & 1);
            #pragma unroll
            for (int m = 1; m < 64; m <<= 1) cc += __shfl_xor(cc, m, 64);
            if ((tid & 63) == 0 && cc) atomicAdd(&cnt[k], cc);
        }
    }
    __syncthreads();

    // ---- ctx closed form (768 items on 512 threads: STRIDED) ----
    const float* pb = part + (p * 4) * 896;
    for (int i = tid; i < 768; i += 512) {
        const int c = i & 127, k = i >> 7;
        float Sall = pb[6 * 128 + c] + pb[896 + 6 * 128 + c] +
                     pb[2 * 896 + 6 * 128 + c] + pb[3 * 896 + 6 * 128 + c];
        float Sk = pb[k * 128 + c] + pb[896 + k * 128 + c] +
                   pb[2 * 896 + k * 128 + c] + pb[3 * 896 + k * 128 + c];
        float Z = fmaf((float)cnt[k], E_M1, 1024.f);
        ct[k][c] = (Sall + E_M1 * Sk) / Z;
    }
    __syncthreads();

    // ---- LN over C + gelu -> centersT; fused nearest-proto argmin ----
    const int wv = tid >> 6, lane = tid & 63;
    if (wv < 6) {
        float x0 = ct[wv][lane], x1 = ct[wv][lane + 64];
        float s = x0 + x1;
        #pragma unroll
        for (int m = 1; m < 64; m <<= 1) s += __shfl_xor(s, m, 64);
        float mu = s * (1.f / 128.f);
        float d0 = x0 - mu, d1 = x1 - mu;
        float ss = d0 * d0 + d1 * d1;
        #pragma unroll
        for (int m = 1; m < 64; m <<= 1) ss += __shfl_xor(ss, m, 64);
        float inv = 1.f / sqrtf(ss * (1.f / 128.f) + 1e-6f);
        float y0 = d0 * inv * g1[lane] + b1[lane];
        float y1 = d1 * inv * g1[lane + 64] + b1[lane + 64];
        float z0 = gelu_exact(y0);
        float z1 = gelu_exact(y1);
        const int row = (b * 16 + pp) * 6 + wv;
        centersT[lane * 768 + row] = z0;
        centersT[(lane + 64) * 768 + row] = z1;

        // argmin over 48 protos (strict < : first index wins, matches jnp)
        float best = INFINITY; int bi = 0;
        for (int k = 0; k < 48; ++k) {
            float t0 = z0 - pl[k * 129 + lane];
            float t1 = z1 - pl[k * 129 + 64 + lane];
            float sd = fmaf(t0, t0, t1 * t1);
            #pragma unroll
            for (int m = 1; m < 64; m <<= 1) sd += __shfl_xor(sd, m, 64);
            if (sd < best) { best = sd; bi = k; }
        }
        if (lane == 0) nearest[row] = bi;
    }
}

// ---------------------------------------------------------------------------
// kernD: momentum scan (parallel over k, ordered predicated loop) + pn2
// ---------------------------------------------------------------------------
__global__ __launch_bounds__(128) void kernD(
    const float* __restrict__ proto0, const int* __restrict__ nearest,
    const float* __restrict__ centersT,
    float* __restrict__ proto_new, float* __restrict__ pn2,
    float* __restrict__ out_expand, float* __restrict__ out_proto)
{
    __shared__ int nl[768];
    __shared__ float wred[2];
    const int k = blockIdx.x, c = threadIdx.x;
    for (int i = c; i < 768; i += 128) nl[i] = nearest[i];
    __syncthreads();
    float p = proto0[k * 128 + c];
    const float OM = (float)(1.0 - 0.999);
    const float* col = centersT + c * 768;
    #pragma unroll 4
    for (int i = 0; i < 768; i += 4) {
        float4 v = *(const float4*)(col + i);
        if (nl[i + 0] == k) p = 0.999f * p + OM * v.x;
        if (nl[i + 1] == k) p = 0.999f * p + OM * v.y;
        if (nl[i + 2] == k) p = 0.999f * p + OM * v.z;
        if (nl[i + 3] == k) p = 0.999f * p + OM * v.w;
    }
    proto_new[k * 128 + c] = p;
    out_proto[k * 128 + c] = p;
    #pragma unroll
    for (int b = 0; b < 8; ++b) out_expand[(b * 48 + k) * 128 + c] = p;
    float sq = p * p;
    #pragma unroll
    for (int m = 1; m < 64; m <<= 1) sq += __shfl_xor(sq, m, 64);
    if ((c & 63) == 0) wred[c >> 6] = sq;
    __syncthreads();
    if (c == 0) pn2[k] = wred[0] + wred[1];
}

// ---------------------------------------------------------------------------
// kernE v3: dot-form distances. 64-n tile, thread = 4n x 3k.
// grid (256 n-tiles, 8 b) x 256 threads. LDS ~60KB (dst aliases dead fT).
// ---------------------------------------------------------------------------
__global__ __launch_bounds__(256) void kernE(
    const float* __restrict__ feats, const float* __restrict__ proto_new,
    const float* __restrict__ pn2g,
    const float* __restrict__ g2, const float* __restrict__ b2,
    float* __restrict__ out_sim, float* __restrict__ out_dist,
    float* __restrict__ pred_small)
{
    __shared__ float fT[128 * 64];     // 32 KB; aliased as dst after main loop
    __shared__ float prot[48 * 132];   // 25.3 KB, padded rows (bank spread)
    __shared__ float p4[4 * 64];
    __shared__ float F2[64];
    __shared__ float muv[64], invv[64];
    float* dst = fT;                   // [n][49], only after post-loop barrier

    const int t = threadIdx.x;
    const int b = blockIdx.y;
    const int nbase = blockIdx.x * 64;

    for (int i = t; i < 6144; i += 256)
        prot[(i >> 7) * 132 + (i & 127)] = proto_new[i];
    #pragma unroll
    for (int it = 0; it < 8; ++it) {
        int idx = it * 256 + t;              // 0..2047
        int c = idx >> 4, qd = idx & 15;
        float4 v = *(const float4*)(feats + (((long long)(b * 128 + c)) << 14) + nbase + qd * 4);
        *(float4*)&fT[c * 64 + qd * 4] = v;
    }
    __syncthreads();

    {   // F2[n] = sum_c f^2 (4 partials x 32 channels)
        int n = t & 63, cg = t >> 6;
        float s = 0.f;
        for (int c = cg * 32; c < cg * 32 + 32; ++c) { float x = fT[c * 64 + n]; s = fmaf(x, x, s); }
        p4[cg * 64 + n] = s;
    }
    __syncthreads();
    if (t < 64) F2[t] = ((p4[t] + p4[64 + t]) + p4[128 + t]) + p4[192 + t];

    const int n4 = (t & 15) * 4, k0 = (t >> 4) * 3;
    v2f acc[3][2];
    #pragma unroll
    for (int j = 0; j < 3; ++j) { acc[j][0] = splat2(0.f); acc[j][1] = splat2(0.f); }

    #pragma unroll 4
    for (int cq = 0; cq < 32; ++cq) {
        const int cb = cq * 4;
        float4 f0 = *(const float4*)&fT[(cb + 0) * 64 + n4];
        float4 f1 = *(const float4*)&fT[(cb + 1) * 64 + n4];
        float4 f2 = *(const float4*)&fT[(cb + 2) * 64 + n4];
        float4 f3 = *(const float4*)&fT[(cb + 3) * 64 + n4];
        v2f f0l = *(v2f*)&f0.x, f0h = *(v2f*)&f0.z;
        v2f f1l = *(v2f*)&f1.x, f1h = *(v2f*)&f1.z;
        v2f f2l = *(v2f*)&f2.x, f2h = *(v2f*)&f2.z;
        v2f f3l = *(v2f*)&f3.x, f3h = *(v2f*)&f3.z;
        #pragma unroll
        for (int j = 0; j < 3; ++j) {
            float4 pv = *(const float4*)&prot[(k0 + j) * 132 + cb];
            v2f px = splat2(pv.x), py = splat2(pv.y), pz = splat2(pv.z), pw = splat2(pv.w);
            acc[j][0] = __builtin_elementwise_fma(f0l, px,
                        __builtin_elementwise_fma(f1l, py,
                        __builtin_elementwise_fma(f2l, pz,
                        __builtin_elementwise_fma(f3l, pw, acc[j][0]))));
            acc[j][1] = __builtin_elementwise_fma(f0h, px,
                        __builtin_elementwise_fma(f1h, py,
                        __builtin_elementwise_fma(f2h, pz,
                        __builtin_elementwise_fma(f3h, pw, acc[j][1]))));
        }
    }
    __syncthreads();   // fT dead from here; region becomes dst

    float f2r0 = F2[n4 + 0], f2r1 = F2[n4 + 1], f2r2 = F2[n4 + 2], f2r3 = F2[n4 + 3];
    #pragma unroll
    for (int j = 0; j < 3; ++j) {
        const int k = k0 + j;
        float pk = pn2g[k];
        float d0 = sqrtf(fmaxf(f2r0 + pk - 2.f * acc[j][0].x, 0.f));
        float d1 = sqrtf(fmaxf(f2r1 + pk - 2.f * acc[j][0].y, 0.f));
        float d2 = sqrtf(fmaxf(f2r2 + pk - 2.f * acc[j][1].x, 0.f));
        float d3 = sqrtf(fmaxf(f2r3 + pk - 2.f * acc[j][1].y, 0.f));
        float4 dv; dv.x = d0; dv.y = d1; dv.z = d2; dv.w = d3;
        *(float4*)(out_dist + (((long long)(b * 48 + k)) << 14) + nbase + n4) = dv;
        dst[(n4 + 0) * 49 + k] = 1.f / (1.f + 2.f * d0);
        dst[(n4 + 1) * 49 + k] = 1.f / (1.f + 2.f * d1);
        dst[(n4 + 2) * 49 + k] = 1.f / (1.f + 2.f * d2);
        dst[(n4 + 3) * 49 + k] = 1.f / (1.f + 2.f * d3);
    }
    __syncthreads();

    if (t < 64) {   // LN stats per n
        const int n = t;
        float s = 0.f;
        for (int k = 0; k < 48; ++k) s += dst[n * 49 + k];
        float mu = s * (1.f / 48.f);
        float s2 = 0.f;
        for (int k = 0; k < 48; ++k) { float d = dst[n * 49 + k] - mu; s2 = fmaf(d, d, s2); }
        muv[n] = mu;
        invv[n] = 1.f / sqrtf(s2 * (1.f / 48.f) + 1e-6f);
    }
    __syncthreads();

    // epilogue: 384 = (c6, n) items on 256 threads
    #pragma unroll
    for (int base = 0; base < 384; base += 256) {
        int i = base + t;
        if (i < 384) {
            const int c6 = i >> 6, n = i & 63, ng = nbase + n;
            float mu = muv[n], inv = invv[n];
            float pm = 0.f;
            #pragma unroll
            for (int kp = 0; kp < 8; ++kp) {
                int k = kp * 6 + c6;
                float y = (dst[n * 49 + k] - mu) * inv * g2[k] + b2[k];
                float z = gelu_exact(y);
                out_sim[(((long long)(b * 48 + k)) << 14) + ng] = z;
                pm = (kp == 0) ? z : fmaxf(pm, z);
            }
            pred_small[((b * 6 + c6) << 14) + ng] = pm;
        }
    }
}

// ---------------------------------------------------------------------------
// kernF: half-pixel bilinear x4 upsample (8,6,128,128)->(8,6,512,512)
// ---------------------------------------------------------------------------
__global__ __launch_bounds__(256) void kernF(
    const float* __restrict__ ps, float* __restrict__ pred)
{
    int idx = blockIdx.x * 256 + threadIdx.x;    // 3,145,728
    int xq = idx & 127;
    int oy = (idx >> 7) & 511;
    int bc = idx >> 16;
    int qy = oy >> 2, ry = oy & 3;
    int y0 = qy + ((ry < 2) ? -1 : 0);
    float fy = (ry == 0) ? 0.625f : (ry == 1) ? 0.875f : (ry == 2) ? 0.125f : 0.375f;
    int y0c = max(y0, 0), y1c = min(y0 + 1, 127);
    const float* base = ps + bc * 16384;
    const float* rA = base + y0c * 128;
    const float* rB = base + y1c * 128;
    int xm = max(xq - 1, 0), xp = min(xq + 1, 127);
    float a0 = rA[xm], a1 = rA[xq], a2 = rA[xp];
    float c0 = rB[xm], c1 = rB[xq], c2 = rB[xp];
    float w0 = 1.f - fy;
    float gm = w0 * a0 + fy * c0;
    float gc = w0 * a1 + fy * c1;
    float gp = w0 * a2 + fy * c2;
    float4 o;
    o.x = 0.375f * gm + 0.625f * gc;
    o.y = 0.125f * gm + 0.875f * gc;
    o.z = 0.875f * gc + 0.125f * gp;
    o.w = 0.625f * gc + 0.375f * gp;
    *(float4*)(pred + ((long long)idx << 2)) = o;
}

// ---------------------------------------------------------------------------
extern "C" void kernel_launch(void* const* d_in, const int* in_sizes, int n_in,
                              void* d_out, int out_size, void* d_ws, size_t ws_size,
                              hipStream_t stream)
{
    const float* feats = (const float*)d_in[0];
    const int* gt = (const int*)d_in[1];
    const float* proto = (const float*)d_in[2];
    const float* g1 = (const float*)d_in[3];
    const float* b1 = (const float*)d_in[4];
    const float* g2 = (const float*)d_in[5];
    const float* b2 = (const float*)d_in[6];

    float* out = (float*)d_out;
    float* pred       = out;
    float* out_expand = out + 12582912;
    float* out_sim    = out + 12632064;
    float* out_dist   = out + 18923520;
    float* out_proto  = out + 25214976;

    float* ws = (float*)d_ws;
    float* centersT   = ws + 98304;             // 98,304 (slot 0 unused)
    float* proto_new  = ws + 196608;            // 6,144
    float* pn2        = ws + 202752;            // 64
    int*   nearest    = (int*)(ws + 202816);    // 768
    float* part       = ws + 203584;            // 512*896 = 458,752
    float* pred_small = ws + 203584;            // ALIASED: kernE writes after
                                                // kernA2's last read of part
    unsigned char* maskb = (unsigned char*)(ws + 990016); // 131,072 B

    kern0b<<<512, 256, 0, stream>>>(gt, maskb);
    kernA1<<<512, 128, 0, stream>>>(feats, maskb, part);
    kernA2<<<128, 512, 0, stream>>>(part, maskb, proto, g1, b1, centersT, nearest);
    kernD <<<48, 128, 0, stream>>>(proto, nearest, centersT, proto_new, pn2,
                                   out_expand, out_proto);
    kernE <<<dim3(256, 8), 256, 0, stream>>>(feats, proto_new, pn2, g2, b2,
                                             out_sim, out_dist, pred_small);
    kernF <<<12288, 256, 0, stream>>>(pred_small, pred);
}